// Round 1
// 154.668 us; speedup vs baseline: 1.0272x; 1.0272x over previous
//
#include <hip/hip_runtime.h>
#include <math.h>

#define D 64
#define CH 256              // owned edges per block
#define HALO 32             // >= max idx_vi segment length (actual ~10)
#define WSZ (CH + HALO)     // edge window per block (288)

// ---------------- K0: zero out[] and row_sum[] ----------------
__global__ void k_zero(float4* __restrict__ out4, float* __restrict__ row_sum,
                       int BN4, int Bn)
{
    const int i = blockIdx.x * 256 + threadIdx.x;
    if (i < BN4) out4[i] = make_float4(0.f, 0.f, 0.f, 0.f);
    if (i < Bn) row_sum[i] = 0.f;
}

// ---------------- K1: fused logits + segment softmax + scatter + rowsum ----------------
// Phase A: 16 lanes x float4 per edge, 8 edges/wave/iter -> logits into LDS.
// Edges are sorted by (idx, vi) so idx_vi segments are contiguous runs
// (avg 1.75 edges, max ~10 << HALO). A block owns every segment whose START
// lies in [b0, b0+CH); its window [b0, b0+CH+HALO) provably contains all
// edges of owned segments. Phase B: block-local softmax + atomic scatter.
__global__ __launch_bounds__(256) void k_fused(
    const int* __restrict__ sel, const float* __restrict__ hc,
    const float* __restrict__ hu, const float* __restrict__ re,
    const float* __restrict__ wsm, const float* __restrict__ bias,
    const float* __restrict__ out_w, const float* __restrict__ out_b,
    const float* __restrict__ na, const float* __restrict__ edges_y,
    float* __restrict__ out, float* __restrict__ row_sum,
    int E, int N)
{
    __shared__ float s_logit[WSZ];
    __shared__ int   s_ivi[WSZ];
    __shared__ float s_row[8];

    const int b0 = blockIdx.x * CH;
    const int Wc = min(WSZ, E - b0);          // valid edges in this window

    const int lane = threadIdx.x & 63;
    const int g    = lane >> 4;               // edge-group within wave (0..3)
    const int d16  = lane & 15;               // lane within group; d = d16*4 .. +3
    const int wv   = threadIdx.x >> 6;        // wave within block (0..3)

    if (threadIdx.x < 8) s_row[threadIdx.x] = 0.f;

    // hoist constants into registers
    const float4* wsm4 = (const float4*)wsm;
    float4 Wk[8];
    #pragma unroll
    for (int k = 0; k < 8; ++k) Wk[k] = wsm4[k * 16 + d16];
    const float4 Bv = ((const float4*)bias)[d16];
    const float4 Ow = ((const float4*)out_w)[d16];
    const float4 Ob = ((const float4*)out_b)[d16];
    const float* Wf  = (const float*)Wk;
    const float* Bvf = (const float*)&Bv;
    const float* Owf = (const float*)&Ow;
    const float* Obf = (const float*)&Ob;

    const float4* hc4 = (const float4*)hc;
    const float4* hu4 = (const float4*)hu;
    const float4* re4 = (const float4*)re;

    // ---------- Phase A: logits for window -> LDS ----------
    #pragma unroll 1
    for (int t = 0; t < (WSZ + 31) / 32; ++t) {          // 9 iters x 32 edges/block
        const int j0 = t * 32 + wv * 8 + g;
        const int j1 = j0 + 4;
        const bool v0 = (j0 < Wc);
        const bool v1 = (j1 < Wc);
        const int ec0 = v0 ? (b0 + j0) : (E - 1);
        const int ec1 = v1 ? (b0 + j1) : (E - 1);

        // issue all index loads first
        const int4 sA0 = *(const int4*)(sel + (size_t)ec0 * 8);
        const int4 sB0 = *(const int4*)(sel + (size_t)ec0 * 8 + 4);
        const int4 sA1 = *(const int4*)(sel + (size_t)ec1 * 8);
        const int4 sB1 = *(const int4*)(sel + (size_t)ec1 * 8 + 4);

        // issue all 10 gathers (independent -> 10 VMEM in flight)
        const float4 a0  = hc4[(size_t)sB0.z * 16 + d16];
        const float4 c0  = hc4[(size_t)sB0.w * 16 + d16];
        const float4 ui0 = hu4[(size_t)sA0.y * 16 + d16];
        const float4 uj0 = hu4[(size_t)sA0.z * 16 + d16];
        const float4 r0  = re4[(size_t)sA0.w * 16 + d16];
        const float4 a1  = hc4[(size_t)sB1.z * 16 + d16];
        const float4 c1  = hc4[(size_t)sB1.w * 16 + d16];
        const float4 ui1 = hu4[(size_t)sA1.y * 16 + d16];
        const float4 uj1 = hu4[(size_t)sA1.z * 16 + d16];
        const float4 r1  = re4[(size_t)sA1.w * 16 + d16];

        float acc0 = 0.f, acc1 = 0.f;
        {
            const float* ap = (const float*)&a0;  const float* cp = (const float*)&c0;
            const float* up = (const float*)&ui0; const float* vp = (const float*)&uj0;
            const float* rp = (const float*)&r0;
            #pragma unroll
            for (int k4 = 0; k4 < 4; ++k4) {
                const float hcvi = ap[k4], hcvj = cp[k4], huvi = up[k4], huvj = vp[k4], rr = rp[k4];
                const float hcr = hcvi * rr, hur = huvi * rr;
                float f = Bvf[k4];
                f += Wf[0*4+k4] * (hcvi * hcvj);
                f += Wf[1*4+k4] * (hcr  * hcvj);
                f += Wf[2*4+k4] * (hcvi * huvj);
                f += Wf[3*4+k4] * (hcr  * huvj);
                f += Wf[4*4+k4] * (huvi * hcvj);
                f += Wf[5*4+k4] * (hur  * hcvj);
                f += Wf[6*4+k4] * (huvi * huvj);
                f += Wf[7*4+k4] * (hur  * huvj);
                acc0 += fmaxf(f, 0.f) * Owf[k4] + Obf[k4];
            }
        }
        {
            const float* ap = (const float*)&a1;  const float* cp = (const float*)&c1;
            const float* up = (const float*)&ui1; const float* vp = (const float*)&uj1;
            const float* rp = (const float*)&r1;
            #pragma unroll
            for (int k4 = 0; k4 < 4; ++k4) {
                const float hcvi = ap[k4], hcvj = cp[k4], huvi = up[k4], huvj = vp[k4], rr = rp[k4];
                const float hcr = hcvi * rr, hur = huvi * rr;
                float f = Bvf[k4];
                f += Wf[0*4+k4] * (hcvi * hcvj);
                f += Wf[1*4+k4] * (hcr  * hcvj);
                f += Wf[2*4+k4] * (hcvi * huvj);
                f += Wf[3*4+k4] * (hcr  * huvj);
                f += Wf[4*4+k4] * (huvi * hcvj);
                f += Wf[5*4+k4] * (hur  * hcvj);
                f += Wf[6*4+k4] * (huvi * huvj);
                f += Wf[7*4+k4] * (hur  * huvj);
                acc1 += fmaxf(f, 0.f) * Owf[k4] + Obf[k4];
            }
        }

        // reduce across the 16 lanes of each group (xor stays within the group)
        #pragma unroll
        for (int off = 8; off > 0; off >>= 1) {
            acc0 += __shfl_xor(acc0, off, 64);
            acc1 += __shfl_xor(acc1, off, 64);
        }

        if (d16 == 0) {
            if (v0) { s_logit[j0] = acc0; s_ivi[j0] = sB0.x; }
            if (v1) { s_logit[j1] = acc1; s_ivi[j1] = sB1.x; }
        }
    }

    __syncthreads();

    // ---------- Phase B: block-local segment softmax + scatter ----------
    // idx_vi of the edge just before the window (for genuine-start detection)
    const int ivi_prev = (b0 > 0) ? sel[((size_t)b0 - 1) * 8 + 4] : -1;

    for (int j = threadIdx.x; j < Wc; j += 256) {
        const int myivi = s_ivi[j];

        // backward scan to segment start within window
        int s = j;
        while (s > 0 && s_ivi[s - 1] == myivi) --s;
        // genuine start at s==0 only if the window boundary is a real boundary
        const bool genuine = (s > 0) || (myivi != ivi_prev);
        if (!genuine || s >= CH) continue;     // segment owned by another block

        // forward scan to segment end (owned segments always fit: len <= HALO)
        int en = j + 1;
        while (en < Wc && s_ivi[en] == myivi) ++en;

        float m = s_logit[j];
        for (int i = s; i < en; ++i) m = fmaxf(m, s_logit[i]);
        float sum = 0.f;
        for (int i = s; i < en; ++i) sum += __expf(s_logit[i] - m);

        const int e = b0 + j;
        const int4 A = *(const int4*)(sel + (size_t)e * 8);   // idx, vi, vj, rel (L1-hot)
        const float ta = na[(size_t)A.x * N + A.y]
                       * (__expf(s_logit[j] - m) / sum) * edges_y[e];

        atomicAdd(out + (size_t)A.x * N + A.z, ta);
        if (A.x < 8) atomicAdd(&s_row[A.x], ta);
        else         atomicAdd(row_sum + A.x, ta);
    }

    __syncthreads();
    if (threadIdx.x < 8) {
        const float v = s_row[threadIdx.x];
        if (v != 0.f) atomicAdd(row_sum + threadIdx.x, v);
    }
}

// ---------------- K4: normalize rows (float4, 2D grid) ----------------
__global__ void k_norm(float4* __restrict__ out, const float* __restrict__ row_sum, int N4) {
    const int col = blockIdx.x * blockDim.x + threadIdx.x;
    const int row = blockIdx.y;
    if (col < N4) {
        const float inv = 1.f / row_sum[row];
        const size_t i = (size_t)row * N4 + col;
        float4 v = out[i];
        v.x *= inv; v.y *= inv; v.z *= inv; v.w *= inv;
        out[i] = v;
    }
}

extern "C" void kernel_launch(void* const* d_in, const int* in_sizes, int n_in,
                              void* d_out, int out_size, void* d_ws, size_t ws_size,
                              hipStream_t stream)
{
    const float* na    = (const float*)d_in[0];   // (B,N)
    const int*   sel   = (const int*)  d_in[1];   // (E,8)
    const float* ey    = (const float*)d_in[2];   // (E,)
    const float* hc    = (const float*)d_in[3];   // (n_visited, D)
    const float* hu    = (const float*)d_in[4];   // (1,N,D)
    const float* re    = (const float*)d_in[5];   // (R,D)
    const float* wsm   = (const float*)d_in[6];   // (8,D)
    const float* bias  = (const float*)d_in[7];   // (D,)
    const float* ow    = (const float*)d_in[8];   // (D,)
    const float* ob    = (const float*)d_in[9];   // (D,)

    float* out = (float*)d_out;

    const int E  = in_sizes[2];
    const int N  = in_sizes[4] / D;   // hidden_uncon = N*D
    const int BN = in_sizes[0];       // B*N
    const int Bn = BN / N;

    // workspace: row_sum (B floats)
    float* row_sum = (float*)d_ws;

    const int N4  = N / 4;
    const int BN4 = BN / 4;

    k_zero<<<(BN4 + 255) / 256, 256, 0, stream>>>((float4*)out, row_sum, BN4, Bn);

    const int nblk = (E + CH - 1) / CH;
    k_fused<<<nblk, 256, 0, stream>>>(sel, hc, hu, re, wsm, bias, ow, ob,
                                      na, ey, out, row_sum, E, N);

    dim3 ngrid((N4 + 255) / 256, Bn);
    k_norm<<<ngrid, 256, 0, stream>>>((float4*)out, row_sum, N4);
}